// Round 1
// baseline (742.532 us; speedup 1.0000x reference)
//
#include <hip/hip_runtime.h>
#include <cstdint>

#define LOG2E 1.44269504088896340736f

typedef __bf16 bf16x8 __attribute__((ext_vector_type(8)));
typedef __bf16 bf16x4 __attribute__((ext_vector_type(4)));
typedef float  f32x4  __attribute__((ext_vector_type(4)));

__device__ __forceinline__ void lds_load16(const void* g, void* l) {
  __builtin_amdgcn_global_load_lds(
      (const __attribute__((address_space(1))) unsigned int*)g,
      (__attribute__((address_space(3))) unsigned int*)l, 16, 0, 0);
}

__device__ __forceinline__ float grp16_max(float v) {
  v = fmaxf(v, __shfl_xor(v, 1));
  v = fmaxf(v, __shfl_xor(v, 2));
  v = fmaxf(v, __shfl_xor(v, 4));
  v = fmaxf(v, __shfl_xor(v, 8));
  return v;
}
__device__ __forceinline__ float grp16_sum(float v) {
  v += __shfl_xor(v, 1);
  v += __shfl_xor(v, 2);
  v += __shfl_xor(v, 4);
  v += __shfl_xor(v, 8);
  return v;
}

// ---------------- fp32 -> bf16 conversion ----------------
__global__ void f2bf_kernel(const float* __restrict__ in, __bf16* __restrict__ out, int n4) {
  int i = blockIdx.x * blockDim.x + threadIdx.x;
  if (i >= n4) return;
  const float4 v = reinterpret_cast<const float4*>(in)[i];
  bf16x4 o;
  o[0] = (__bf16)v.x; o[1] = (__bf16)v.y; o[2] = (__bf16)v.z; o[3] = (__bf16)v.w;
  reinterpret_cast<bf16x4*>(out)[i] = o;
}

// ---------------- GEMM: C = A @ B^T (+bias), A[M][K], B[N][K], bf16 in ----------------
// EPI==0: scatter to Q/K/V [B, NH, S, D] bf16, Q scaled by 1/sqrt(D)
// EPI==1: plain fp32 output [M][N]
template <int EPI>
__global__ __launch_bounds__(256)
void gemm_bt(const __bf16* __restrict__ A, const __bf16* __restrict__ Bm,
             int M, int N, int K, const float* __restrict__ bias,
             __bf16* __restrict__ qo, __bf16* __restrict__ ko, __bf16* __restrict__ vo,
             float* __restrict__ co)
{
  __shared__ __align__(16) __bf16 As[128 * 32];
  __shared__ __align__(16) __bf16 Bs[128 * 32];
  const int t = threadIdx.x;
  const int lane = t & 63, w = t >> 6;
  const int g = lane >> 4, r16 = lane & 15;
  const int tM = blockIdx.y * 128, tN = blockIdx.x * 128;
  const int wrow = (w >> 1) * 64, wcol = (w & 1) * 64;

  f32x4 acc[4][4] = {};
  const char* Ag = (const char*)A + (size_t)tM * K * 2;
  const char* Bg = (const char*)Bm + (size_t)tN * K * 2;
  const int ldb = K * 2;

  for (int k0 = 0; k0 < K; k0 += 32) {
    const char* Ak = Ag + (size_t)k0 * 2;
    const char* Bk = Bg + (size_t)k0 * 2;
#pragma unroll
    for (int it = 0; it < 2; it++) {
      int o = it * 4096 + t * 16;
      lds_load16(Ak + (size_t)(o >> 6) * ldb + (o & 63), (char*)As + o);
    }
#pragma unroll
    for (int it = 0; it < 2; it++) {
      int o = it * 4096 + t * 16;
      lds_load16(Bk + (size_t)(o >> 6) * ldb + (o & 63), (char*)Bs + o);
    }
    __syncthreads();
    bf16x8 af[4], bfr[4];
#pragma unroll
    for (int i = 0; i < 4; i++) af[i]  = *(const bf16x8*)&As[(wrow + i * 16 + r16) * 32 + g * 8];
#pragma unroll
    for (int i = 0; i < 4; i++) bfr[i] = *(const bf16x8*)&Bs[(wcol + i * 16 + r16) * 32 + g * 8];
#pragma unroll
    for (int i = 0; i < 4; i++)
#pragma unroll
      for (int j = 0; j < 4; j++)
        acc[i][j] = __builtin_amdgcn_mfma_f32_16x16x32_bf16(af[i], bfr[j], acc[i][j], 0, 0, 0);
    __syncthreads();
  }

  if (EPI == 0) {
#pragma unroll
    for (int j = 0; j < 4; j++) {
      int col = tN + wcol + j * 16 + r16;
      float bv = bias[col];
      int which = col >> 11;          // 0=Q 1=K 2=V
      int f = col & 2047;
      int head = f >> 7, dd = f & 127;
      __bf16* dst = (which == 0) ? qo : (which == 1) ? ko : vo;
      float sc = (which == 0) ? 0.08838834764831845f : 1.0f;
#pragma unroll
      for (int i = 0; i < 4; i++) {
#pragma unroll
        for (int r = 0; r < 4; r++) {
          int m = tM + wrow + i * 16 + g * 4 + r;
          int bb = m >> 11, s = m & 2047;
          float v = (acc[i][j][r] + bv) * sc;
          dst[((size_t)(bb * 16 + head) * 2048 + s) * 128 + dd] = (__bf16)v;
        }
      }
    }
  } else {
#pragma unroll
    for (int j = 0; j < 4; j++) {
      int col = tN + wcol + j * 16 + r16;
      float bv = bias[col];
#pragma unroll
      for (int i = 0; i < 4; i++) {
#pragma unroll
        for (int r = 0; r < 4; r++) {
          int m = tM + wrow + i * 16 + g * 4 + r;
          co[(size_t)m * N + col] = acc[i][j][r] + bv;
        }
      }
    }
  }
}

// ---------------- causal flash attention ----------------
// grid: x = q-tile (S/64 = 32), y = b*NH + head (32). 256 threads = 4 waves.
// Q/K/V: [B*NH, S, D] bf16 (scale folded into Q). Out: [B*S, H] bf16.
__global__ __launch_bounds__(256)
void attn_kernel(const __bf16* __restrict__ Qb, const __bf16* __restrict__ Kb,
                 const __bf16* __restrict__ Vb, __bf16* __restrict__ Ob)
{
  const int qi = blockIdx.x;
  const int bh = blockIdx.y;
  const int b = bh >> 4, head = bh & 15;
  const int t = threadIdx.x, lane = t & 63, w = t >> 6;
  const int g = lane >> 4, r16 = lane & 15;

  __shared__ __align__(16) __bf16 Ks[64 * 128];     // XOR-swizzled content
  __shared__ __align__(16) __bf16 Vt[128 * 72];     // transposed [d][k], pad to 72
  __shared__ __align__(16) __bf16 Ps[4][16 * 72];   // per-wave P, pad to 72

  const size_t hoff = (size_t)bh * 2048 * 128;
  const int q0 = qi * 64;

  bf16x8 qf[4];
  {
    const __bf16* qp = Qb + hoff + (size_t)(q0 + w * 16 + r16) * 128 + g * 8;
#pragma unroll
    for (int ks = 0; ks < 4; ks++) qf[ks] = *(const bf16x8*)(qp + ks * 32);
  }

  f32x4 oacc[8] = {};
  float m_run[4], l_run[4];
#pragma unroll
  for (int r = 0; r < 4; r++) { m_run[r] = -1e30f; l_run[r] = 0.f; }

  const char* Kt0 = (const char*)(Kb + hoff);
  const __bf16* Vt0 = Vb + hoff;

  for (int kt = 0; kt <= qi; kt++) {
    __syncthreads();
    // stage K: 16 KB via global_load_lds, XOR-swizzle via pre-swizzled SOURCE (linear dest)
#pragma unroll
    for (int it = 0; it < 4; it++) {
      int o = it * 4096 + t * 16;
      int swz = o ^ (((o >> 8) & 7) << 4);
      lds_load16(Kt0 + (size_t)kt * 16384 + swz, (char*)Ks + o);
    }
    // stage V transposed (reg-staged): Vt[d][k]
#pragma unroll
    for (int it = 0; it < 4; it++) {
      int row = (t >> 4) + it * 16;
      int c0 = (t & 15) * 8;
      bf16x8 vv = *(const bf16x8*)(Vt0 + ((size_t)kt * 64 + row) * 128 + c0);
#pragma unroll
      for (int j = 0; j < 8; j++) Vt[(c0 + j) * 72 + row] = vv[j];
    }
    __syncthreads();

    // S = Q K^T (scale already folded into Q)
    f32x4 sf[4];
#pragma unroll
    for (int ni = 0; ni < 4; ni++) {
      f32x4 a = {};
#pragma unroll
      for (int ks = 0; ks < 4; ks++) {
        int row = ni * 16 + r16;
        int off = (row * 256 + (ks * 32 + g * 8) * 2) ^ ((row & 7) << 4);
        bf16x8 kf = *(const bf16x8*)((const char*)Ks + off);
        a = __builtin_amdgcn_mfma_f32_16x16x32_bf16(qf[ks], kf, a, 0, 0, 0);
      }
      sf[ni] = a;
    }

    // causal mask (only bites on the diagonal tile)
#pragma unroll
    for (int ni = 0; ni < 4; ni++) {
      int kg = kt * 64 + ni * 16 + r16;
#pragma unroll
      for (int r = 0; r < 4; r++) {
        int qg = q0 + w * 16 + g * 4 + r;
        if (kg > qg) sf[ni][r] = -1e30f;
      }
    }

    // online softmax (row stats shared across each 16-lane group)
#pragma unroll
    for (int r = 0; r < 4; r++) {
      float mx = fmaxf(fmaxf(sf[0][r], sf[1][r]), fmaxf(sf[2][r], sf[3][r]));
      mx = grp16_max(mx);
      float mn = fmaxf(m_run[r], mx);
      float alpha = __builtin_amdgcn_exp2f((m_run[r] - mn) * LOG2E);
      float ps = 0.f;
#pragma unroll
      for (int ni = 0; ni < 4; ni++) {
        float p = __builtin_amdgcn_exp2f((sf[ni][r] - mn) * LOG2E);
        sf[ni][r] = p; ps += p;
      }
      ps = grp16_sum(ps);
      l_run[r] = l_run[r] * alpha + ps;
      m_run[r] = mn;
#pragma unroll
      for (int di = 0; di < 8; di++) oacc[di][r] *= alpha;
    }

    // P -> LDS (wave-private region) to convert C-layout -> A-layout
#pragma unroll
    for (int ni = 0; ni < 4; ni++)
#pragma unroll
      for (int r = 0; r < 4; r++)
        Ps[w][(g * 4 + r) * 72 + ni * 16 + r16] = (__bf16)sf[ni][r];
    __syncthreads();

    // O += P @ V
#pragma unroll
    for (int ks2 = 0; ks2 < 2; ks2++) {
      bf16x8 pa = *(const bf16x8*)&Ps[w][r16 * 72 + ks2 * 32 + g * 8];
#pragma unroll
      for (int di = 0; di < 8; di++) {
        bf16x8 vf = *(const bf16x8*)&Vt[(di * 16 + r16) * 72 + ks2 * 32 + g * 8];
        oacc[di] = __builtin_amdgcn_mfma_f32_16x16x32_bf16(pa, vf, oacc[di], 0, 0, 0);
      }
    }
  }

  // epilogue: O / l, write [B*S, H] bf16
#pragma unroll
  for (int r = 0; r < 4; r++) {
    float inv = 1.0f / l_run[r];
    size_t rowb = ((size_t)b * 2048 + q0 + w * 16 + g * 4 + r) * 2048 + head * 128 + r16;
#pragma unroll
    for (int di = 0; di < 8; di++)
      Ob[rowb + di * 16] = (__bf16)(oacc[di][r] * inv);
  }
}

// ---------------- host ----------------
extern "C" void kernel_launch(void* const* d_in, const int* in_sizes, int n_in,
                              void* d_out, int out_size, void* d_ws, size_t ws_size,
                              hipStream_t stream) {
  const float* X  = (const float*)d_in[0];   // [2,2048,2048]
  const float* Wi = (const float*)d_in[1];   // [6144,2048]
  const float* bi = (const float*)d_in[2];   // [6144]
  const float* Wo = (const float*)d_in[3];   // [2048,2048]
  const float* bo = (const float*)d_in[4];   // [2048]
  float* out = (float*)d_out;                // [2,2048,2048] fp32

  char* p = (char*)d_ws;
  auto alloc = [&](size_t bytes) {
    char* r = p;
    p += (bytes + 255) & ~(size_t)255;
    return r;
  };
  __bf16* Xb  = (__bf16*)alloc((size_t)4096 * 2048 * 2);
  __bf16* Wib = (__bf16*)alloc((size_t)6144 * 2048 * 2);
  __bf16* Wob = (__bf16*)alloc((size_t)2048 * 2048 * 2);
  __bf16* Qb  = (__bf16*)alloc((size_t)32 * 2048 * 128 * 2);
  __bf16* Kb  = (__bf16*)alloc((size_t)32 * 2048 * 128 * 2);
  __bf16* Vb  = (__bf16*)alloc((size_t)32 * 2048 * 128 * 2);
  __bf16* Ab  = (__bf16*)alloc((size_t)4096 * 2048 * 2);

  {
    int n4 = 4096 * 2048 / 4;
    f2bf_kernel<<<(n4 + 255) / 256, 256, 0, stream>>>(X, Xb, n4);
  }
  {
    int n4 = 6144 * 2048 / 4;
    f2bf_kernel<<<(n4 + 255) / 256, 256, 0, stream>>>(Wi, Wib, n4);
  }
  {
    int n4 = 2048 * 2048 / 4;
    f2bf_kernel<<<(n4 + 255) / 256, 256, 0, stream>>>(Wo, Wob, n4);
  }

  gemm_bt<0><<<dim3(48, 32), 256, 0, stream>>>(Xb, Wib, 4096, 6144, 2048, bi,
                                               Qb, Kb, Vb, nullptr);
  attn_kernel<<<dim3(32, 32), 256, 0, stream>>>(Qb, Kb, Vb, Ab);
  gemm_bt<1><<<dim3(16, 32), 256, 0, stream>>>(Ab, Wob, 4096, 2048, 2048, bo,
                                               nullptr, nullptr, nullptr, out);
}

// Round 2
// 489.817 us; speedup vs baseline: 1.5159x; 1.5159x over previous
//
#include <hip/hip_runtime.h>
#include <cstdint>

typedef __bf16 bf16x8 __attribute__((ext_vector_type(8)));
typedef __bf16 bf16x4 __attribute__((ext_vector_type(4)));
typedef float  f32x4  __attribute__((ext_vector_type(4)));

__device__ __forceinline__ void lds_load16(const void* g, void* l) {
  __builtin_amdgcn_global_load_lds(
      (const __attribute__((address_space(1))) unsigned int*)g,
      (__attribute__((address_space(3))) unsigned int*)l, 16, 0, 0);
}

__device__ __forceinline__ float grp16_max(float v) {
  v = fmaxf(v, __shfl_xor(v, 1));
  v = fmaxf(v, __shfl_xor(v, 2));
  v = fmaxf(v, __shfl_xor(v, 4));
  v = fmaxf(v, __shfl_xor(v, 8));
  return v;
}
__device__ __forceinline__ float grp16_sum(float v) {
  v += __shfl_xor(v, 1);
  v += __shfl_xor(v, 2);
  v += __shfl_xor(v, 4);
  v += __shfl_xor(v, 8);
  return v;
}

// ---------------- fp32 -> bf16 conversion ----------------
__global__ void f2bf_kernel(const float* __restrict__ in, __bf16* __restrict__ out, int n4) {
  int i = blockIdx.x * blockDim.x + threadIdx.x;
  if (i >= n4) return;
  const float4 v = reinterpret_cast<const float4*>(in)[i];
  bf16x4 o;
  o[0] = (__bf16)v.x; o[1] = (__bf16)v.y; o[2] = (__bf16)v.z; o[3] = (__bf16)v.w;
  reinterpret_cast<bf16x4*>(out)[i] = o;
}

// ---------------- GEMM: C = A @ B^T (+bias), A[M][K], B[N][K], bf16 in ----------------
// EPI==0: scatter Q,K -> [B,NH,S,D] bf16 (Q scaled by log2e/sqrt(D)), V -> [B,NH,D,S] (transposed)
// EPI==1: plain fp32 output [M][N]
template <int EPI>
__global__ __launch_bounds__(256)
void gemm_bt(const __bf16* __restrict__ A, const __bf16* __restrict__ Bm,
             int M, int N, int K, const float* __restrict__ bias,
             __bf16* __restrict__ qo, __bf16* __restrict__ ko, __bf16* __restrict__ vo,
             float* __restrict__ co)
{
  __shared__ __align__(16) __bf16 As[128 * 32];
  __shared__ __align__(16) __bf16 Bs[128 * 32];
  const int t = threadIdx.x;
  const int lane = t & 63, w = t >> 6;
  const int g = lane >> 4, r16 = lane & 15;
  const int tM = blockIdx.y * 128, tN = blockIdx.x * 128;
  const int wrow = (w >> 1) * 64, wcol = (w & 1) * 64;

  f32x4 acc[4][4] = {};
  const char* Ag = (const char*)A + (size_t)tM * K * 2;
  const char* Bg = (const char*)Bm + (size_t)tN * K * 2;
  const int ldb = K * 2;

  for (int k0 = 0; k0 < K; k0 += 32) {
    const char* Ak = Ag + (size_t)k0 * 2;
    const char* Bk = Bg + (size_t)k0 * 2;
#pragma unroll
    for (int it = 0; it < 2; it++) {
      int o = it * 4096 + t * 16;
      lds_load16(Ak + (size_t)(o >> 6) * ldb + (o & 63), (char*)As + o);
    }
#pragma unroll
    for (int it = 0; it < 2; it++) {
      int o = it * 4096 + t * 16;
      lds_load16(Bk + (size_t)(o >> 6) * ldb + (o & 63), (char*)Bs + o);
    }
    __syncthreads();
    bf16x8 af[4], bfr[4];
#pragma unroll
    for (int i = 0; i < 4; i++) af[i]  = *(const bf16x8*)&As[(wrow + i * 16 + r16) * 32 + g * 8];
#pragma unroll
    for (int i = 0; i < 4; i++) bfr[i] = *(const bf16x8*)&Bs[(wcol + i * 16 + r16) * 32 + g * 8];
#pragma unroll
    for (int i = 0; i < 4; i++)
#pragma unroll
      for (int j = 0; j < 4; j++)
        acc[i][j] = __builtin_amdgcn_mfma_f32_16x16x32_bf16(af[i], bfr[j], acc[i][j], 0, 0, 0);
    __syncthreads();
  }

  if (EPI == 0) {
#pragma unroll
    for (int j = 0; j < 4; j++) {
      int col = tN + wcol + j * 16 + r16;
      float bv = bias[col];
      int which = col >> 11;          // 0=Q 1=K 2=V
      int f = col & 2047;
      int head = f >> 7, dd = f & 127;
      if (which == 2) {
        // V^T: [bh][d][s]
#pragma unroll
        for (int i = 0; i < 4; i++) {
#pragma unroll
          for (int r = 0; r < 4; r++) {
            int m = tM + wrow + i * 16 + g * 4 + r;
            int bb = m >> 11, s = m & 2047;
            vo[((size_t)(bb * 16 + head) * 128 + dd) * 2048 + s] = (__bf16)(acc[i][j][r] + bv);
          }
        }
      } else {
        __bf16* dst = (which == 0) ? qo : ko;
        // Q scale = log2e / sqrt(128) (exp2-domain softmax)
        float sc = (which == 0) ? 0.12751757f : 1.0f;
#pragma unroll
        for (int i = 0; i < 4; i++) {
#pragma unroll
          for (int r = 0; r < 4; r++) {
            int m = tM + wrow + i * 16 + g * 4 + r;
            int bb = m >> 11, s = m & 2047;
            dst[((size_t)(bb * 16 + head) * 2048 + s) * 128 + dd] = (__bf16)((acc[i][j][r] + bv) * sc);
          }
        }
      }
    }
  } else {
#pragma unroll
    for (int j = 0; j < 4; j++) {
      int col = tN + wcol + j * 16 + r16;
      float bv = bias[col];
#pragma unroll
      for (int i = 0; i < 4; i++) {
#pragma unroll
        for (int r = 0; r < 4; r++) {
          int m = tM + wrow + i * 16 + g * 4 + r;
          co[(size_t)m * N + col] = acc[i][j][r] + bv;
        }
      }
    }
  }
}

// ---------------- causal flash attention, paired q-tiles ----------------
// grid: x = pair index pi (16): q-tiles qiS=pi, qiL=31-pi. y = b*NH+head (32).
// 256 threads = 4 waves; each wave owns 16 q-rows of each tile.
// Q: [bh][s][d] bf16 (scale*log2e folded). K: [bh][s][d]. V^T: [bh][d][s]. Out: [B*S][H] bf16.
__global__ __launch_bounds__(256)
void attn_kernel(const __bf16* __restrict__ Qb, const __bf16* __restrict__ Kb,
                 const __bf16* __restrict__ Vb, __bf16* __restrict__ Ob)
{
  const int pi = blockIdx.x;
  const int bh = blockIdx.y;
  const int b = bh >> 4, head = bh & 15;
  const int t = threadIdx.x, lane = t & 63, w = t >> 6;
  const int g = lane >> 4, r16 = lane & 15;

  __shared__ __align__(16) __bf16 Ks[2][64 * 128];   // swizzled K tile  [s][d]
  __shared__ __align__(16) __bf16 Vs[2][128 * 64];   // swizzled V^T tile [d][s]
  __shared__ __align__(16) __bf16 Ps[4][16 * 72];    // per-wave P scratch

  const int qiS = pi, qiL = 31 - pi;
  const int q0S = qiS * 64, q0L = qiL * 64;

  const size_t hoff = (size_t)bh * 2048 * 128;
  const char* Kt0 = (const char*)(Kb + hoff);
  const char* Vt0 = (const char*)(Vb + hoff);

  bf16x8 qfL[4], qfS[4];
  {
    const __bf16* qp = Qb + hoff + (size_t)(q0L + w * 16 + r16) * 128 + g * 8;
#pragma unroll
    for (int ks = 0; ks < 4; ks++) qfL[ks] = *(const bf16x8*)(qp + ks * 32);
    const __bf16* qp2 = Qb + hoff + (size_t)(q0S + w * 16 + r16) * 128 + g * 8;
#pragma unroll
    for (int ks = 0; ks < 4; ks++) qfS[ks] = *(const bf16x8*)(qp2 + ks * 32);
  }

  f32x4 oL[8] = {}, oS[8] = {};
  float mL[4], lL[4], mS[4], lS[4];
#pragma unroll
  for (int r = 0; r < 4; r++) { mL[r] = -1e30f; lL[r] = 0.f; mS[r] = -1e30f; lS[r] = 0.f; }

#define STAGE(bb_, kt_) do {                                                   \
  const char* kg_ = Kt0 + (size_t)(kt_) * 16384;                               \
  const char* vg_ = Vt0 + (size_t)(kt_) * 128;                                 \
  _Pragma("unroll")                                                            \
  for (int it = 0; it < 4; it++) {                                             \
    int o = it * 4096 + t * 16;                                                \
    int swz = o ^ (((o >> 8) & 7) << 4);                                       \
    lds_load16(kg_ + swz, (char*)Ks[bb_] + o);                                 \
  }                                                                            \
  _Pragma("unroll")                                                            \
  for (int it = 0; it < 4; it++) {                                             \
    int o = it * 4096 + t * 16;                                                \
    int swz = o ^ (((o >> 7) & 7) << 4);                                       \
    lds_load16(vg_ + (size_t)(swz >> 7) * 4096 + (swz & 127), (char*)Vs[bb_] + o); \
  }                                                                            \
} while (0)

#define TILE_COMPUTE(qfX, oX, mX, lX, q0X, isDiag, bb_) do {                   \
  f32x4 sf[4];                                                                 \
  _Pragma("unroll")                                                            \
  for (int ni = 0; ni < 4; ni++) {                                             \
    f32x4 a = {};                                                              \
    _Pragma("unroll")                                                          \
    for (int ks = 0; ks < 4; ks++) {                                           \
      int row = ni * 16 + r16;                                                 \
      int off = (row * 256 + (ks * 32 + g * 8) * 2) ^ ((row & 7) << 4);        \
      bf16x8 kf = *(const bf16x8*)((const char*)Ks[bb_] + off);                \
      a = __builtin_amdgcn_mfma_f32_16x16x32_bf16(qfX[ks], kf, a, 0, 0, 0);    \
    }                                                                          \
    sf[ni] = a;                                                                \
  }                                                                            \
  if (isDiag) {                                                                \
    _Pragma("unroll")                                                          \
    for (int ni = 0; ni < 4; ni++) {                                           \
      int kg2 = kt * 64 + ni * 16 + r16;                                       \
      _Pragma("unroll")                                                        \
      for (int r = 0; r < 4; r++) {                                            \
        int qg = q0X + w * 16 + g * 4 + r;                                     \
        if (kg2 > qg) sf[ni][r] = -1e30f;                                      \
      }                                                                        \
    }                                                                          \
  }                                                                            \
  _Pragma("unroll")                                                            \
  for (int r = 0; r < 4; r++) {                                                \
    float mx = fmaxf(fmaxf(sf[0][r], sf[1][r]), fmaxf(sf[2][r], sf[3][r]));    \
    mx = grp16_max(mx);                                                        \
    float mn = fmaxf(mX[r], mx);                                               \
    float alpha = __builtin_amdgcn_exp2f(mX[r] - mn);                          \
    float ps = 0.f;                                                            \
    _Pragma("unroll")                                                          \
    for (int ni = 0; ni < 4; ni++) {                                           \
      float p = __builtin_amdgcn_exp2f(sf[ni][r] - mn);                        \
      sf[ni][r] = p; ps += p;                                                  \
    }                                                                          \
    ps = grp16_sum(ps);                                                        \
    lX[r] = lX[r] * alpha + ps;                                                \
    mX[r] = mn;                                                                \
    _Pragma("unroll")                                                          \
    for (int di = 0; di < 8; di++) oX[di][r] *= alpha;                         \
  }                                                                            \
  _Pragma("unroll")                                                            \
  for (int ni = 0; ni < 4; ni++)                                               \
    _Pragma("unroll")                                                          \
    for (int r = 0; r < 4; r++)                                                \
      Ps[w][(g * 4 + r) * 72 + ni * 16 + r16] = (__bf16)sf[ni][r];             \
  _Pragma("unroll")                                                            \
  for (int ks2 = 0; ks2 < 2; ks2++) {                                          \
    bf16x8 pa = *(const bf16x8*)&Ps[w][r16 * 72 + ks2 * 32 + g * 8];           \
    _Pragma("unroll")                                                          \
    for (int di = 0; di < 8; di++) {                                           \
      int d_ = di * 16 + r16;                                                  \
      int off = ((d_ << 7) + (ks2 * 32 + g * 8) * 2) ^ ((d_ & 7) << 4);        \
      bf16x8 vf = *(const bf16x8*)((const char*)Vs[bb_] + off);                \
      oX[di] = __builtin_amdgcn_mfma_f32_16x16x32_bf16(pa, vf, oX[di], 0, 0, 0); \
    }                                                                          \
  }                                                                            \
} while (0)

  STAGE(0, 0);
  __syncthreads();

  for (int kt = 0; kt <= qiL; ++kt) {
    const int bb = kt & 1;
    if (kt < qiL) STAGE(bb ^ 1, kt + 1);
    TILE_COMPUTE(qfL, oL, mL, lL, q0L, (kt == qiL), bb);
    if (kt <= qiS) TILE_COMPUTE(qfS, oS, mS, lS, q0S, (kt == qiS), bb);
    __syncthreads();
  }

#undef STAGE
#undef TILE_COMPUTE

  // epilogue: O / l, write [B*S][H] bf16
#pragma unroll
  for (int r = 0; r < 4; r++) {
    float invL = 1.0f / lL[r];
    size_t rowL = ((size_t)b * 2048 + q0L + w * 16 + g * 4 + r) * 2048 + head * 128 + r16;
#pragma unroll
    for (int di = 0; di < 8; di++)
      Ob[rowL + di * 16] = (__bf16)(oL[di][r] * invL);
    float invS = 1.0f / lS[r];
    size_t rowS = ((size_t)b * 2048 + q0S + w * 16 + g * 4 + r) * 2048 + head * 128 + r16;
#pragma unroll
    for (int di = 0; di < 8; di++)
      Ob[rowS + di * 16] = (__bf16)(oS[di][r] * invS);
  }
}

// ---------------- host ----------------
extern "C" void kernel_launch(void* const* d_in, const int* in_sizes, int n_in,
                              void* d_out, int out_size, void* d_ws, size_t ws_size,
                              hipStream_t stream) {
  const float* X  = (const float*)d_in[0];   // [2,2048,2048]
  const float* Wi = (const float*)d_in[1];   // [6144,2048]
  const float* bi = (const float*)d_in[2];   // [6144]
  const float* Wo = (const float*)d_in[3];   // [2048,2048]
  const float* bo = (const float*)d_in[4];   // [2048]
  float* out = (float*)d_out;                // [2,2048,2048] fp32

  char* p = (char*)d_ws;
  auto alloc = [&](size_t bytes) {
    char* r = p;
    p += (bytes + 255) & ~(size_t)255;
    return r;
  };
  __bf16* Xb  = (__bf16*)alloc((size_t)4096 * 2048 * 2);
  __bf16* Wib = (__bf16*)alloc((size_t)6144 * 2048 * 2);
  __bf16* Wob = (__bf16*)alloc((size_t)2048 * 2048 * 2);
  __bf16* Qb  = (__bf16*)alloc((size_t)32 * 2048 * 128 * 2);
  __bf16* Kb  = (__bf16*)alloc((size_t)32 * 2048 * 128 * 2);
  __bf16* Vb  = (__bf16*)alloc((size_t)32 * 2048 * 128 * 2);   // transposed [bh][d][s]
  __bf16* Ab  = (__bf16*)alloc((size_t)4096 * 2048 * 2);

  {
    int n4 = 4096 * 2048 / 4;
    f2bf_kernel<<<(n4 + 255) / 256, 256, 0, stream>>>(X, Xb, n4);
  }
  {
    int n4 = 6144 * 2048 / 4;
    f2bf_kernel<<<(n4 + 255) / 256, 256, 0, stream>>>(Wi, Wib, n4);
  }
  {
    int n4 = 2048 * 2048 / 4;
    f2bf_kernel<<<(n4 + 255) / 256, 256, 0, stream>>>(Wo, Wob, n4);
  }

  gemm_bt<0><<<dim3(48, 32), 256, 0, stream>>>(Xb, Wib, 4096, 6144, 2048, bi,
                                               Qb, Kb, Vb, nullptr);
  attn_kernel<<<dim3(16, 32), 256, 0, stream>>>(Qb, Kb, Vb, Ab);
  gemm_bt<1><<<dim3(16, 32), 256, 0, stream>>>(Ab, Wob, 4096, 2048, 2048, bo,
                                               nullptr, nullptr, nullptr, out);
}

// Round 3
// 471.648 us; speedup vs baseline: 1.5743x; 1.0385x over previous
//
#include <hip/hip_runtime.h>
#include <cstdint>

typedef __bf16 bf16x8 __attribute__((ext_vector_type(8)));
typedef __bf16 bf16x4 __attribute__((ext_vector_type(4)));
typedef float  f32x4  __attribute__((ext_vector_type(4)));

__device__ __forceinline__ void lds_load16(const void* g, void* l) {
  __builtin_amdgcn_global_load_lds(
      (const __attribute__((address_space(1))) unsigned int*)g,
      (__attribute__((address_space(3))) unsigned int*)l, 16, 0, 0);
}

#define BAR() do { asm volatile("" ::: "memory"); __builtin_amdgcn_s_barrier(); asm volatile("" ::: "memory"); } while (0)

__device__ __forceinline__ float grp16_max(float v) {
  v = fmaxf(v, __shfl_xor(v, 1));
  v = fmaxf(v, __shfl_xor(v, 2));
  v = fmaxf(v, __shfl_xor(v, 4));
  v = fmaxf(v, __shfl_xor(v, 8));
  return v;
}
__device__ __forceinline__ float grp16_sum(float v) {
  v += __shfl_xor(v, 1);
  v += __shfl_xor(v, 2);
  v += __shfl_xor(v, 4);
  v += __shfl_xor(v, 8);
  return v;
}

// ---------------- fp32 -> bf16 conversion ----------------
__global__ void f2bf_kernel(const float* __restrict__ in, __bf16* __restrict__ out, int n4) {
  int i = blockIdx.x * blockDim.x + threadIdx.x;
  if (i >= n4) return;
  const float4 v = reinterpret_cast<const float4*>(in)[i];
  bf16x4 o;
  o[0] = (__bf16)v.x; o[1] = (__bf16)v.y; o[2] = (__bf16)v.z; o[3] = (__bf16)v.w;
  reinterpret_cast<bf16x4*>(out)[i] = o;
}

// ================= 256x256 8-phase GEMM (QKV producer) =================
// C = A @ B^T + bias. A[M][K], B[N][K] bf16. 512 threads = 8 waves (2M x 4N).
// BM=BN=256, BK=64. LDS 128 KiB: [buf][A|B][256][64] bf16, rows XOR-swizzled
// (byte ^= (row&7)<<4) via pre-swizzled global source (linear gload_lds dest).
// Phase structure per K-tile (counted vmcnt(4) at tile end; see derivation):
//  ph1: ds_read A-frags 0-3 + B-frags 0-1 (12); stage next-tile B-half0 -> buf^1
//  ph2: ds_read A-frags 4-7 + B-frags 2-3 (12); stage next-tile B-half1 -> buf^1
//  ph3: stage next-next-tile A-half0 -> buf (safe: no LDS reads after ph2)
//  ph4: ds_read B-frags 0-1 again (4); stage next-next A-half1 -> buf; vmcnt(4)
__global__ __launch_bounds__(512, 1)
void gemm256_qkv(const __bf16* __restrict__ A, const __bf16* __restrict__ Bm,
                 const float* __restrict__ bias,
                 __bf16* __restrict__ qo, __bf16* __restrict__ ko, __bf16* __restrict__ vo)
{
  constexpr int K = 2048, NT = K / 64;
  __shared__ __align__(16) char lds8[131072];

  const int t = threadIdx.x;
  const int lane = t & 63, w = t >> 6;
  const int g = lane >> 4, r16 = lane & 15;
  const int wm = w >> 2, wn = w & 3;

  // XCD-aware swizzle (384 % 8 == 0 -> simple form), tn-major grouping
  const int bid = blockIdx.x;
  const int swz = (bid & 7) * 48 + (bid >> 3);
  const int tM = (swz & 15) * 256;
  const int tN = (swz >> 4) * 256;

  const char* Ag = (const char*)A + (size_t)tM * K * 2;
  const char* Bg = (const char*)Bm + (size_t)tN * K * 2;
  const int ld = K * 2;

  // staging: per call, one 16KB half-tile (2 chunks/thread)
  auto STAGE_HALF = [&](int X, int h, int tb, int ktg) {
#pragma unroll
    for (int i = 0; i < 2; i++) {
      int o = i * 8192 + t * 16;
      int rl = o >> 7;
      int inrow = (o & 127) ^ ((rl & 7) << 4);
      const char* src = (X ? Bg : Ag) + (size_t)(h * 128 + rl) * ld + (size_t)ktg * 128 + inrow;
      lds_load16(src, lds8 + tb * 65536 + X * 32768 + h * 16384 + o);
    }
  };

  // fragment LDS offsets
  const int xorv = (r16 & 7) << 4;
  const int aoff0 = (g * 16) ^ xorv;          // ks=0 in-row byte; ks=1 = aoff0 ^ 64

  f32x4 acc[8][4] = {};
  bf16x8 af[8][2];
  bf16x8 bfm[2][2];

  // ---- prologue: tile0 full + tile1 A-halves; vmcnt(4) leaves tile1 A in flight
  STAGE_HALF(0, 0, 0, 0); STAGE_HALF(0, 1, 0, 0);
  STAGE_HALF(1, 0, 0, 0); STAGE_HALF(1, 1, 0, 0);
  STAGE_HALF(0, 0, 1, 1); STAGE_HALF(0, 1, 1, 1);
  asm volatile("s_waitcnt vmcnt(4)" ::: "memory");
  __builtin_amdgcn_s_barrier();

  for (int kt = 0; kt < NT; ++kt) {
    const int cb = kt & 1;
    const char* aT = lds8 + cb * 65536;
    const char* bT = aT + 32768;
    const int arow = (wm * 128 + r16) * 128;
    const int brow = (wn * 64 + r16) * 128;

    // ---- phase 1: quadrant (mf 0-3) x (nf 0-1)
#pragma unroll
    for (int mf = 0; mf < 4; mf++) {
#pragma unroll
      for (int ks = 0; ks < 2; ks++)
        af[mf][ks] = *(const bf16x8*)(aT + arow + mf * 2048 + (aoff0 ^ (ks * 64)));
    }
#pragma unroll
    for (int nf = 0; nf < 2; nf++) {
#pragma unroll
      for (int ks = 0; ks < 2; ks++)
        bfm[nf][ks] = *(const bf16x8*)(bT + brow + nf * 2048 + (aoff0 ^ (ks * 64)));
    }
    if (kt + 1 < NT) STAGE_HALF(1, 0, cb ^ 1, kt + 1);
    BAR();
    __builtin_amdgcn_s_setprio(1);
#pragma unroll
    for (int mf = 0; mf < 4; mf++)
#pragma unroll
      for (int nf = 0; nf < 2; nf++)
#pragma unroll
        for (int ks = 0; ks < 2; ks++)
          acc[mf][nf] = __builtin_amdgcn_mfma_f32_16x16x32_bf16(af[mf][ks], bfm[nf][ks], acc[mf][nf], 0, 0, 0);
    __builtin_amdgcn_s_setprio(0);
    BAR();

    // ---- phase 2: quadrant (mf 4-7) x (nf 2-3)
#pragma unroll
    for (int mf = 4; mf < 8; mf++) {
#pragma unroll
      for (int ks = 0; ks < 2; ks++)
        af[mf][ks] = *(const bf16x8*)(aT + arow + mf * 2048 + (aoff0 ^ (ks * 64)));
    }
#pragma unroll
    for (int nf = 0; nf < 2; nf++) {
#pragma unroll
      for (int ks = 0; ks < 2; ks++)
        bfm[nf][ks] = *(const bf16x8*)(bT + brow + (nf + 2) * 2048 + (aoff0 ^ (ks * 64)));
    }
    if (kt + 1 < NT) STAGE_HALF(1, 1, cb ^ 1, kt + 1);
    BAR();
    __builtin_amdgcn_s_setprio(1);
#pragma unroll
    for (int mf = 4; mf < 8; mf++)
#pragma unroll
      for (int nf = 0; nf < 2; nf++)
#pragma unroll
        for (int ks = 0; ks < 2; ks++)
          acc[mf][nf + 2] = __builtin_amdgcn_mfma_f32_16x16x32_bf16(af[mf][ks], bfm[nf][ks], acc[mf][nf + 2], 0, 0, 0);
    __builtin_amdgcn_s_setprio(0);
    BAR();

    // ---- phase 3: quadrant (mf 0-3) x (nf 2-3), regs only
    if (kt + 2 < NT) STAGE_HALF(0, 0, cb, kt + 2);
    BAR();
    __builtin_amdgcn_s_setprio(1);
#pragma unroll
    for (int mf = 0; mf < 4; mf++)
#pragma unroll
      for (int nf = 0; nf < 2; nf++)
#pragma unroll
        for (int ks = 0; ks < 2; ks++)
          acc[mf][nf + 2] = __builtin_amdgcn_mfma_f32_16x16x32_bf16(af[mf][ks], bfm[nf][ks], acc[mf][nf + 2], 0, 0, 0);
    __builtin_amdgcn_s_setprio(0);
    BAR();

    // ---- phase 4: quadrant (mf 4-7) x (nf 0-1); re-read B 0-1 (safe: A-halves only being written)
#pragma unroll
    for (int nf = 0; nf < 2; nf++) {
#pragma unroll
      for (int ks = 0; ks < 2; ks++)
        bfm[nf][ks] = *(const bf16x8*)(bT + brow + nf * 2048 + (aoff0 ^ (ks * 64)));
    }
    if (kt + 2 < NT) STAGE_HALF(0, 1, cb, kt + 2);
    BAR();
    __builtin_amdgcn_s_setprio(1);
#pragma unroll
    for (int mf = 4; mf < 8; mf++)
#pragma unroll
      for (int nf = 0; nf < 2; nf++)
#pragma unroll
        for (int ks = 0; ks < 2; ks++)
          acc[mf][nf] = __builtin_amdgcn_mfma_f32_16x16x32_bf16(af[mf][ks], bfm[nf][ks], acc[mf][nf], 0, 0, 0);
    __builtin_amdgcn_s_setprio(0);
    if (kt + 2 < NT) { asm volatile("s_waitcnt vmcnt(4)" ::: "memory"); }
    else             { asm volatile("s_waitcnt vmcnt(0)" ::: "memory"); }
    BAR();
  }

  // ---- epilogue: QKV scatter (Q scaled by log2e/sqrt(D), V transposed [bh][d][s])
#pragma unroll
  for (int nf = 0; nf < 4; nf++) {
    int col = tN + wn * 64 + nf * 16 + r16;
    float bv = bias[col];
    int which = col >> 11;
    int f = col & 2047;
    int head = f >> 7, dd = f & 127;
    if (which == 2) {
#pragma unroll
      for (int mf = 0; mf < 8; mf++) {
#pragma unroll
        for (int r = 0; r < 4; r++) {
          int m = tM + wm * 128 + mf * 16 + g * 4 + r;
          int bb2 = m >> 11, s = m & 2047;
          vo[((size_t)(bb2 * 16 + head) * 128 + dd) * 2048 + s] = (__bf16)(acc[mf][nf][r] + bv);
        }
      }
    } else {
      __bf16* dst = (which == 0) ? qo : ko;
      float sc = (which == 0) ? 0.12751757f : 1.0f;   // log2e / sqrt(128) folded into Q
#pragma unroll
      for (int mf = 0; mf < 8; mf++) {
#pragma unroll
        for (int r = 0; r < 4; r++) {
          int m = tM + wm * 128 + mf * 16 + g * 4 + r;
          int bb2 = m >> 11, s = m & 2047;
          dst[((size_t)(bb2 * 16 + head) * 2048 + s) * 128 + dd] = (__bf16)((acc[mf][nf][r] + bv) * sc);
        }
      }
    }
  }
}

// ================= 128x128 GEMM (output projection), 4-way-swizzled LDS =================
__global__ __launch_bounds__(256)
void gemm_bt_f32(const __bf16* __restrict__ A, const __bf16* __restrict__ Bm,
                 int M, int N, int K, const float* __restrict__ bias, float* __restrict__ co)
{
  __shared__ __align__(16) __bf16 As[128 * 32];
  __shared__ __align__(16) __bf16 Bs[128 * 32];
  const int t = threadIdx.x;
  const int lane = t & 63, w = t >> 6;
  const int g = lane >> 4, r16 = lane & 15;
  const int tM = blockIdx.y * 128, tN = blockIdx.x * 128;
  const int wrow = (w >> 1) * 64, wcol = (w & 1) * 64;

  f32x4 acc[4][4] = {};
  const char* Ag = (const char*)A + (size_t)tM * K * 2;
  const char* Bg = (const char*)Bm + (size_t)tN * K * 2;
  const int ldb = K * 2;
  const int soff = ((r16 & 3) << 4);   // read-side XOR

  for (int k0 = 0; k0 < K; k0 += 32) {
    const char* Ak = Ag + (size_t)k0 * 2;
    const char* Bk = Bg + (size_t)k0 * 2;
#pragma unroll
    for (int it = 0; it < 2; it++) {
      int o = it * 4096 + t * 16;
      int rl = o >> 6;
      int inrow = (o & 63) ^ ((rl & 3) << 4);
      lds_load16(Ak + (size_t)rl * ldb + inrow, (char*)As + o);
    }
#pragma unroll
    for (int it = 0; it < 2; it++) {
      int o = it * 4096 + t * 16;
      int rl = o >> 6;
      int inrow = (o & 63) ^ ((rl & 3) << 4);
      lds_load16(Bk + (size_t)rl * ldb + inrow, (char*)Bs + o);
    }
    __syncthreads();
    bf16x8 af[4], bfr[4];
#pragma unroll
    for (int i = 0; i < 4; i++)
      af[i] = *(const bf16x8*)((const char*)As + (wrow + i * 16 + r16) * 64 + ((g * 16) ^ soff));
#pragma unroll
    for (int i = 0; i < 4; i++)
      bfr[i] = *(const bf16x8*)((const char*)Bs + (wcol + i * 16 + r16) * 64 + ((g * 16) ^ soff));
#pragma unroll
    for (int i = 0; i < 4; i++)
#pragma unroll
      for (int j = 0; j < 4; j++)
        acc[i][j] = __builtin_amdgcn_mfma_f32_16x16x32_bf16(af[i], bfr[j], acc[i][j], 0, 0, 0);
    __syncthreads();
  }

#pragma unroll
  for (int j = 0; j < 4; j++) {
    int col = tN + wcol + j * 16 + r16;
    float bv = bias[col];
#pragma unroll
    for (int i = 0; i < 4; i++) {
#pragma unroll
      for (int r = 0; r < 4; r++) {
        int m = tM + wrow + i * 16 + g * 4 + r;
        co[(size_t)m * N + col] = acc[i][j][r] + bv;
      }
    }
  }
}

// ---------------- causal flash attention, paired q-tiles ----------------
__global__ __launch_bounds__(256)
void attn_kernel(const __bf16* __restrict__ Qb, const __bf16* __restrict__ Kb,
                 const __bf16* __restrict__ Vb, __bf16* __restrict__ Ob)
{
  const int pi = blockIdx.x;
  const int bh = blockIdx.y;
  const int b = bh >> 4, head = bh & 15;
  const int t = threadIdx.x, lane = t & 63, w = t >> 6;
  const int g = lane >> 4, r16 = lane & 15;

  __shared__ __align__(16) __bf16 Ks[2][64 * 128];
  __shared__ __align__(16) __bf16 Vs[2][128 * 64];
  __shared__ __align__(16) __bf16 Ps[4][16 * 72];

  const int qiS = pi, qiL = 31 - pi;
  const int q0S = qiS * 64, q0L = qiL * 64;

  const size_t hoff = (size_t)bh * 2048 * 128;
  const char* Kt0 = (const char*)(Kb + hoff);
  const char* Vt0 = (const char*)(Vb + hoff);

  bf16x8 qfL[4], qfS[4];
  {
    const __bf16* qp = Qb + hoff + (size_t)(q0L + w * 16 + r16) * 128 + g * 8;
#pragma unroll
    for (int ks = 0; ks < 4; ks++) qfL[ks] = *(const bf16x8*)(qp + ks * 32);
    const __bf16* qp2 = Qb + hoff + (size_t)(q0S + w * 16 + r16) * 128 + g * 8;
#pragma unroll
    for (int ks = 0; ks < 4; ks++) qfS[ks] = *(const bf16x8*)(qp2 + ks * 32);
  }

  f32x4 oL[8] = {}, oS[8] = {};
  float mL[4], lL[4], mS[4], lS[4];
#pragma unroll
  for (int r = 0; r < 4; r++) { mL[r] = -1e30f; lL[r] = 0.f; mS[r] = -1e30f; lS[r] = 0.f; }

#define STAGE(bb_, kt_) do {                                                   \
  const char* kg_ = Kt0 + (size_t)(kt_) * 16384;                               \
  const char* vg_ = Vt0 + (size_t)(kt_) * 128;                                 \
  _Pragma("unroll")                                                            \
  for (int it = 0; it < 4; it++) {                                             \
    int o = it * 4096 + t * 16;                                                \
    int swz = o ^ (((o >> 8) & 7) << 4);                                       \
    lds_load16(kg_ + swz, (char*)Ks[bb_] + o);                                 \
  }                                                                            \
  _Pragma("unroll")                                                            \
  for (int it = 0; it < 4; it++) {                                             \
    int o = it * 4096 + t * 16;                                                \
    int swz = o ^ (((o >> 7) & 7) << 4);                                       \
    lds_load16(vg_ + (size_t)(swz >> 7) * 4096 + (swz & 127), (char*)Vs[bb_] + o); \
  }                                                                            \
} while (0)

#define TILE_COMPUTE(qfX, oX, mX, lX, q0X, isDiag, bb_) do {                   \
  f32x4 sf[4];                                                                 \
  __builtin_amdgcn_s_setprio(1);                                               \
  _Pragma("unroll")                                                            \
  for (int ni = 0; ni < 4; ni++) {                                             \
    f32x4 a = {};                                                              \
    _Pragma("unroll")                                                          \
    for (int ks = 0; ks < 4; ks++) {                                           \
      int row = ni * 16 + r16;                                                 \
      int off = (row * 256 + (ks * 32 + g * 8) * 2) ^ ((row & 7) << 4);        \
      bf16x8 kf = *(const bf16x8*)((const char*)Ks[bb_] + off);                \
      a = __builtin_amdgcn_mfma_f32_16x16x32_bf16(qfX[ks], kf, a, 0, 0, 0);    \
    }                                                                          \
    sf[ni] = a;                                                                \
  }                                                                            \
  __builtin_amdgcn_s_setprio(0);                                               \
  if (isDiag) {                                                                \
    _Pragma("unroll")                                                          \
    for (int ni = 0; ni < 4; ni++) {                                           \
      int kg2 = kt * 64 + ni * 16 + r16;                                       \
      _Pragma("unroll")                                                        \
      for (int r = 0; r < 4; r++) {                                            \
        int qg = q0X + w * 16 + g * 4 + r;                                     \
        if (kg2 > qg) sf[ni][r] = -1e30f;                                      \
      }                                                                        \
    }                                                                          \
  }                                                                            \
  _Pragma("unroll")                                                            \
  for (int r = 0; r < 4; r++) {                                                \
    float mx = fmaxf(fmaxf(sf[0][r], sf[1][r]), fmaxf(sf[2][r], sf[3][r]));    \
    mx = grp16_max(mx);                                                        \
    float mn = fmaxf(mX[r], mx);                                               \
    float alpha = __builtin_amdgcn_exp2f(mX[r] - mn);                          \
    float ps = 0.f;                                                            \
    _Pragma("unroll")                                                          \
    for (int ni = 0; ni < 4; ni++) {                                           \
      float p = __builtin_amdgcn_exp2f(sf[ni][r] - mn);                        \
      sf[ni][r] = p; ps += p;                                                  \
    }                                                                          \
    ps = grp16_sum(ps);                                                        \
    lX[r] = lX[r] * alpha + ps;                                                \
    mX[r] = mn;                                                                \
    _Pragma("unroll")                                                          \
    for (int di = 0; di < 8; di++) oX[di][r] *= alpha;                         \
  }                                                                            \
  _Pragma("unroll")                                                            \
  for (int ni = 0; ni < 4; ni++)                                               \
    _Pragma("unroll")                                                          \
    for (int r = 0; r < 4; r++)                                                \
      Ps[w][(g * 4 + r) * 72 + ni * 16 + r16] = (__bf16)sf[ni][r];             \
  __builtin_amdgcn_s_setprio(1);                                               \
  _Pragma("unroll")                                                            \
  for (int ks2 = 0; ks2 < 2; ks2++) {                                          \
    bf16x8 pa = *(const bf16x8*)&Ps[w][r16 * 72 + ks2 * 32 + g * 8];           \
    _Pragma("unroll")                                                          \
    for (int di = 0; di < 8; di++) {                                           \
      int d_ = di * 16 + r16;                                                  \
      int off = ((d_ << 7) + (ks2 * 32 + g * 8) * 2) ^ ((d_ & 7) << 4);        \
      bf16x8 vf = *(const bf16x8*)((const char*)Vs[bb_] + off);                \
      oX[di] = __builtin_amdgcn_mfma_f32_16x16x32_bf16(pa, vf, oX[di], 0, 0, 0); \
    }                                                                          \
  }                                                                            \
  __builtin_amdgcn_s_setprio(0);                                               \
} while (0)

  STAGE(0, 0);
  __syncthreads();

  for (int kt = 0; kt <= qiL; ++kt) {
    const int bb = kt & 1;
    if (kt < qiL) STAGE(bb ^ 1, kt + 1);
    TILE_COMPUTE(qfL, oL, mL, lL, q0L, (kt == qiL), bb);
    if (kt <= qiS) TILE_COMPUTE(qfS, oS, mS, lS, q0S, (kt == qiS), bb);
    __syncthreads();
  }

#undef STAGE
#undef TILE_COMPUTE

#pragma unroll
  for (int r = 0; r < 4; r++) {
    float invL = 1.0f / lL[r];
    size_t rowL = ((size_t)b * 2048 + q0L + w * 16 + g * 4 + r) * 2048 + head * 128 + r16;
#pragma unroll
    for (int di = 0; di < 8; di++)
      Ob[rowL + di * 16] = (__bf16)(oL[di][r] * invL);
    float invS = 1.0f / lS[r];
    size_t rowS = ((size_t)b * 2048 + q0S + w * 16 + g * 4 + r) * 2048 + head * 128 + r16;
#pragma unroll
    for (int di = 0; di < 8; di++)
      Ob[rowS + di * 16] = (__bf16)(oS[di][r] * invS);
  }
}

// ---------------- host ----------------
extern "C" void kernel_launch(void* const* d_in, const int* in_sizes, int n_in,
                              void* d_out, int out_size, void* d_ws, size_t ws_size,
                              hipStream_t stream) {
  const float* X  = (const float*)d_in[0];
  const float* Wi = (const float*)d_in[1];
  const float* bi = (const float*)d_in[2];
  const float* Wo = (const float*)d_in[3];
  const float* bo = (const float*)d_in[4];
  float* out = (float*)d_out;

  char* p = (char*)d_ws;
  auto alloc = [&](size_t bytes) {
    char* r = p;
    p += (bytes + 255) & ~(size_t)255;
    return r;
  };
  __bf16* Xb  = (__bf16*)alloc((size_t)4096 * 2048 * 2);
  __bf16* Wib = (__bf16*)alloc((size_t)6144 * 2048 * 2);
  __bf16* Wob = (__bf16*)alloc((size_t)2048 * 2048 * 2);
  __bf16* Qb  = (__bf16*)alloc((size_t)32 * 2048 * 128 * 2);
  __bf16* Kb  = (__bf16*)alloc((size_t)32 * 2048 * 128 * 2);
  __bf16* Vb  = (__bf16*)alloc((size_t)32 * 2048 * 128 * 2);   // [bh][d][s]
  __bf16* Ab  = (__bf16*)alloc((size_t)4096 * 2048 * 2);

  {
    int n4 = 4096 * 2048 / 4;
    f2bf_kernel<<<(n4 + 255) / 256, 256, 0, stream>>>(X, Xb, n4);
  }
  {
    int n4 = 6144 * 2048 / 4;
    f2bf_kernel<<<(n4 + 255) / 256, 256, 0, stream>>>(Wi, Wib, n4);
  }
  {
    int n4 = 2048 * 2048 / 4;
    f2bf_kernel<<<(n4 + 255) / 256, 256, 0, stream>>>(Wo, Wob, n4);
  }

  gemm256_qkv<<<dim3(384), 512, 0, stream>>>(Xb, Wib, bi, Qb, Kb, Vb);
  attn_kernel<<<dim3(16, 32), 256, 0, stream>>>(Qb, Kb, Vb, Ab);
  gemm_bt_f32<<<dim3(16, 32), 256, 0, stream>>>(Ab, Wob, 4096, 2048, 2048, bo, out);
}

// Round 4
// 415.260 us; speedup vs baseline: 1.7881x; 1.1358x over previous
//
#include <hip/hip_runtime.h>
#include <cstdint>

typedef __bf16 bf16x8 __attribute__((ext_vector_type(8)));
typedef __bf16 bf16x4 __attribute__((ext_vector_type(4)));
typedef float  f32x4  __attribute__((ext_vector_type(4)));

__device__ __forceinline__ void lds_load16(const void* g, void* l) {
  __builtin_amdgcn_global_load_lds(
      (const __attribute__((address_space(1))) unsigned int*)g,
      (__attribute__((address_space(3))) unsigned int*)l, 16, 0, 0);
}

#define BAR() do { asm volatile("" ::: "memory"); __builtin_amdgcn_s_barrier(); asm volatile("" ::: "memory"); } while (0)

__device__ __forceinline__ float grp16_max(float v) {
  v = fmaxf(v, __shfl_xor(v, 1));
  v = fmaxf(v, __shfl_xor(v, 2));
  v = fmaxf(v, __shfl_xor(v, 4));
  v = fmaxf(v, __shfl_xor(v, 8));
  return v;
}
__device__ __forceinline__ float grp16_sum(float v) {
  v += __shfl_xor(v, 1);
  v += __shfl_xor(v, 2);
  v += __shfl_xor(v, 4);
  v += __shfl_xor(v, 8);
  return v;
}

// ---------------- fp32 -> bf16 conversion ----------------
__global__ void f2bf_kernel(const float* __restrict__ in, __bf16* __restrict__ out, int n4) {
  int i = blockIdx.x * blockDim.x + threadIdx.x;
  if (i >= n4) return;
  const float4 v = reinterpret_cast<const float4*>(in)[i];
  bf16x4 o;
  o[0] = (__bf16)v.x; o[1] = (__bf16)v.y; o[2] = (__bf16)v.z; o[3] = (__bf16)v.w;
  reinterpret_cast<bf16x4*>(out)[i] = o;
}

// ================= 256x256 8-phase GEMM =================
// C = A @ B^T + bias. A[M][K], B[N][K] bf16. 512 threads = 8 waves (2M x 4N).
// EPI==0: QKV scatter (M=4096,N=6144, grid 384). EPI==1: fp32 out (M=4096,N=2048, grid 128).
template <int EPI>
__global__ __launch_bounds__(512, 1)
void gemm256(const __bf16* __restrict__ A, const __bf16* __restrict__ Bm,
             const float* __restrict__ bias,
             __bf16* __restrict__ qo, __bf16* __restrict__ ko, __bf16* __restrict__ vo,
             float* __restrict__ co)
{
  constexpr int K = 2048, NT = K / 64;
  __shared__ __align__(16) char lds8[131072];

  const int t = threadIdx.x;
  const int lane = t & 63, w = t >> 6;
  const int g = lane >> 4, r16 = lane & 15;
  const int wm = w >> 2, wn = w & 3;

  const int bid = blockIdx.x;
  int tM, tN;
  if (EPI == 0) {
    const int swz = (bid & 7) * 48 + (bid >> 3);     // 384 blocks, 16 M-tiles x 24 N-tiles
    tM = (swz & 15) * 256;
    tN = (swz >> 4) * 256;
  } else {
    const int swz = (bid & 7) * 16 + (bid >> 3);     // 128 blocks, 16 M-tiles x 8 N-tiles
    tM = (swz & 15) * 256;
    tN = (swz >> 4) * 256;
  }

  const char* Ag = (const char*)A + (size_t)tM * K * 2;
  const char* Bg = (const char*)Bm + (size_t)tN * K * 2;
  const int ld = K * 2;

  auto STAGE_HALF = [&](int X, int h, int tb, int ktg) {
#pragma unroll
    for (int i = 0; i < 2; i++) {
      int o = i * 8192 + t * 16;
      int rl = o >> 7;
      int inrow = (o & 127) ^ ((rl & 7) << 4);
      const char* src = (X ? Bg : Ag) + (size_t)(h * 128 + rl) * ld + (size_t)ktg * 128 + inrow;
      lds_load16(src, lds8 + tb * 65536 + X * 32768 + h * 16384 + o);
    }
  };

  const int xorv = (r16 & 7) << 4;
  const int aoff0 = (g * 16) ^ xorv;

  f32x4 acc[8][4] = {};
  bf16x8 af[8][2];
  bf16x8 bfm[2][2];

  STAGE_HALF(0, 0, 0, 0); STAGE_HALF(0, 1, 0, 0);
  STAGE_HALF(1, 0, 0, 0); STAGE_HALF(1, 1, 0, 0);
  STAGE_HALF(0, 0, 1, 1); STAGE_HALF(0, 1, 1, 1);
  asm volatile("s_waitcnt vmcnt(4)" ::: "memory");
  __builtin_amdgcn_s_barrier();

  for (int kt = 0; kt < NT; ++kt) {
    const int cb = kt & 1;
    const char* aT = lds8 + cb * 65536;
    const char* bT = aT + 32768;
    const int arow = (wm * 128 + r16) * 128;
    const int brow = (wn * 64 + r16) * 128;

    // phase 1: (mf 0-3) x (nf 0-1)
#pragma unroll
    for (int mf = 0; mf < 4; mf++)
#pragma unroll
      for (int ks = 0; ks < 2; ks++)
        af[mf][ks] = *(const bf16x8*)(aT + arow + mf * 2048 + (aoff0 ^ (ks * 64)));
#pragma unroll
    for (int nf = 0; nf < 2; nf++)
#pragma unroll
      for (int ks = 0; ks < 2; ks++)
        bfm[nf][ks] = *(const bf16x8*)(bT + brow + nf * 2048 + (aoff0 ^ (ks * 64)));
    if (kt + 1 < NT) STAGE_HALF(1, 0, cb ^ 1, kt + 1);
    BAR();
    __builtin_amdgcn_s_setprio(1);
#pragma unroll
    for (int mf = 0; mf < 4; mf++)
#pragma unroll
      for (int nf = 0; nf < 2; nf++)
#pragma unroll
        for (int ks = 0; ks < 2; ks++)
          acc[mf][nf] = __builtin_amdgcn_mfma_f32_16x16x32_bf16(af[mf][ks], bfm[nf][ks], acc[mf][nf], 0, 0, 0);
    __builtin_amdgcn_s_setprio(0);
    BAR();

    // phase 2: (mf 4-7) x (nf 2-3)
#pragma unroll
    for (int mf = 4; mf < 8; mf++)
#pragma unroll
      for (int ks = 0; ks < 2; ks++)
        af[mf][ks] = *(const bf16x8*)(aT + arow + mf * 2048 + (aoff0 ^ (ks * 64)));
#pragma unroll
    for (int nf = 0; nf < 2; nf++)
#pragma unroll
      for (int ks = 0; ks < 2; ks++)
        bfm[nf][ks] = *(const bf16x8*)(bT + brow + (nf + 2) * 2048 + (aoff0 ^ (ks * 64)));
    if (kt + 1 < NT) STAGE_HALF(1, 1, cb ^ 1, kt + 1);
    BAR();
    __builtin_amdgcn_s_setprio(1);
#pragma unroll
    for (int mf = 4; mf < 8; mf++)
#pragma unroll
      for (int nf = 0; nf < 2; nf++)
#pragma unroll
        for (int ks = 0; ks < 2; ks++)
          acc[mf][nf + 2] = __builtin_amdgcn_mfma_f32_16x16x32_bf16(af[mf][ks], bfm[nf][ks], acc[mf][nf + 2], 0, 0, 0);
    __builtin_amdgcn_s_setprio(0);
    BAR();

    // phase 3: (mf 0-3) x (nf 2-3)
    if (kt + 2 < NT) STAGE_HALF(0, 0, cb, kt + 2);
    BAR();
    __builtin_amdgcn_s_setprio(1);
#pragma unroll
    for (int mf = 0; mf < 4; mf++)
#pragma unroll
      for (int nf = 0; nf < 2; nf++)
#pragma unroll
        for (int ks = 0; ks < 2; ks++)
          acc[mf][nf + 2] = __builtin_amdgcn_mfma_f32_16x16x32_bf16(af[mf][ks], bfm[nf][ks], acc[mf][nf + 2], 0, 0, 0);
    __builtin_amdgcn_s_setprio(0);
    BAR();

    // phase 4: (mf 4-7) x (nf 0-1)
#pragma unroll
    for (int nf = 0; nf < 2; nf++)
#pragma unroll
      for (int ks = 0; ks < 2; ks++)
        bfm[nf][ks] = *(const bf16x8*)(bT + brow + nf * 2048 + (aoff0 ^ (ks * 64)));
    if (kt + 2 < NT) STAGE_HALF(0, 1, cb, kt + 2);
    BAR();
    __builtin_amdgcn_s_setprio(1);
#pragma unroll
    for (int mf = 4; mf < 8; mf++)
#pragma unroll
      for (int nf = 0; nf < 2; nf++)
#pragma unroll
        for (int ks = 0; ks < 2; ks++)
          acc[mf][nf] = __builtin_amdgcn_mfma_f32_16x16x32_bf16(af[mf][ks], bfm[nf][ks], acc[mf][nf], 0, 0, 0);
    __builtin_amdgcn_s_setprio(0);
    if (kt + 2 < NT) { asm volatile("s_waitcnt vmcnt(4)" ::: "memory"); }
    else             { asm volatile("s_waitcnt vmcnt(0)" ::: "memory"); }
    BAR();
  }

  if (EPI == 0) {
#pragma unroll
    for (int nf = 0; nf < 4; nf++) {
      int col = tN + wn * 64 + nf * 16 + r16;
      float bv = bias[col];
      int which = col >> 11;
      int f = col & 2047;
      int head = f >> 7, dd = f & 127;
      if (which == 2) {
#pragma unroll
        for (int mf = 0; mf < 8; mf++)
#pragma unroll
          for (int r = 0; r < 4; r++) {
            int m = tM + wm * 128 + mf * 16 + g * 4 + r;
            int bb2 = m >> 11, s = m & 2047;
            vo[((size_t)(bb2 * 16 + head) * 128 + dd) * 2048 + s] = (__bf16)(acc[mf][nf][r] + bv);
          }
      } else {
        __bf16* dst = (which == 0) ? qo : ko;
        float sc = (which == 0) ? 0.12751757f : 1.0f;   // log2e/sqrt(128) folded into Q
#pragma unroll
        for (int mf = 0; mf < 8; mf++)
#pragma unroll
          for (int r = 0; r < 4; r++) {
            int m = tM + wm * 128 + mf * 16 + g * 4 + r;
            int bb2 = m >> 11, s = m & 2047;
            dst[((size_t)(bb2 * 16 + head) * 2048 + s) * 128 + dd] = (__bf16)((acc[mf][nf][r] + bv) * sc);
          }
      }
    }
  } else {
    constexpr int N = 2048;
#pragma unroll
    for (int nf = 0; nf < 4; nf++) {
      int col = tN + wn * 64 + nf * 16 + r16;
      float bv = bias[col];
#pragma unroll
      for (int mf = 0; mf < 8; mf++)
#pragma unroll
        for (int r = 0; r < 4; r++) {
          int m = tM + wm * 128 + mf * 16 + g * 4 + r;
          co[(size_t)m * N + col] = acc[mf][nf][r] + bv;
        }
    }
  }
}

// ---------------- causal flash attention ----------------
// 1D grid 1024: qi = 31 - (bid>>5) (longest-first), bh = bid&31 (bid%8==bh%8 -> XCD locality).
// 256 threads = 4 waves, 16 q-rows/wave. Single-buffered K/V (42 KB LDS, 3 blocks/CU).
__global__ __launch_bounds__(256)
void attn_kernel(const __bf16* __restrict__ Qb, const __bf16* __restrict__ Kb,
                 const __bf16* __restrict__ Vb, __bf16* __restrict__ Ob)
{
  const int bid = blockIdx.x;
  const int qi = 31 - (bid >> 5);
  const int bh = bid & 31;
  const int b = bh >> 4, head = bh & 15;
  const int t = threadIdx.x, lane = t & 63, w = t >> 6;
  const int g = lane >> 4, r16 = lane & 15;

  __shared__ __align__(16) __bf16 Ks[64 * 128];     // swizzled K tile  [s][d]
  __shared__ __align__(16) __bf16 Vs[128 * 64];     // swizzled V^T tile [d][s]
  __shared__ __align__(16) __bf16 Ps[4][16 * 72];   // per-wave P scratch

  const int q0 = qi * 64;
  const size_t hoff = (size_t)bh * 2048 * 128;
  const char* Kt0 = (const char*)(Kb + hoff);
  const char* Vt0 = (const char*)(Vb + hoff);

  bf16x8 qf[4];
  {
    const __bf16* qp = Qb + hoff + (size_t)(q0 + w * 16 + r16) * 128 + g * 8;
#pragma unroll
    for (int ks = 0; ks < 4; ks++) qf[ks] = *(const bf16x8*)(qp + ks * 32);
  }

  f32x4 oacc[8] = {};
  float m_run[4], l_run[4];
#pragma unroll
  for (int r = 0; r < 4; r++) { m_run[r] = -1e30f; l_run[r] = 0.f; }

  for (int kt = 0; kt <= qi; ++kt) {
    // ---- stage K and V^T (linear dest, pre-swizzled source)
#pragma unroll
    for (int it = 0; it < 4; it++) {
      int o = it * 4096 + t * 16;
      int swz = o ^ (((o >> 8) & 7) << 4);
      lds_load16(Kt0 + (size_t)kt * 16384 + swz, (char*)Ks + o);
    }
#pragma unroll
    for (int it = 0; it < 4; it++) {
      int o = it * 4096 + t * 16;
      int swz = o ^ (((o >> 7) & 7) << 4);
      lds_load16(Vt0 + (size_t)kt * 128 + (size_t)(swz >> 7) * 4096 + (swz & 127), (char*)Vs + o);
    }
    __syncthreads();   // drains vmcnt+lgkmcnt, then barrier

    // ---- S = Q K^T
    f32x4 sf[4];
#pragma unroll
    for (int ni = 0; ni < 4; ni++) {
      f32x4 a = {};
#pragma unroll
      for (int ks = 0; ks < 4; ks++) {
        int row = ni * 16 + r16;
        int off = (row * 256 + (ks * 32 + g * 8) * 2) ^ ((row & 7) << 4);
        bf16x8 kf = *(const bf16x8*)((const char*)Ks + off);
        a = __builtin_amdgcn_mfma_f32_16x16x32_bf16(qf[ks], kf, a, 0, 0, 0);
      }
      sf[ni] = a;
    }

    // ---- causal mask (diagonal tile only)
    if (kt == qi) {
#pragma unroll
      for (int ni = 0; ni < 4; ni++) {
        int kg = kt * 64 + ni * 16 + r16;
#pragma unroll
        for (int r = 0; r < 4; r++) {
          int qg = q0 + w * 16 + g * 4 + r;
          if (kg > qg) sf[ni][r] = -1e30f;
        }
      }
    }

    // ---- online softmax (exp2 domain; scale folded into Q)
#pragma unroll
    for (int r = 0; r < 4; r++) {
      float mx = fmaxf(fmaxf(sf[0][r], sf[1][r]), fmaxf(sf[2][r], sf[3][r]));
      mx = grp16_max(mx);
      float mn = fmaxf(m_run[r], mx);
      float alpha = __builtin_amdgcn_exp2f(m_run[r] - mn);
      float ps = 0.f;
#pragma unroll
      for (int ni = 0; ni < 4; ni++) {
        float p = __builtin_amdgcn_exp2f(sf[ni][r] - mn);
        sf[ni][r] = p; ps += p;
      }
      ps = grp16_sum(ps);
      l_run[r] = l_run[r] * alpha + ps;
      m_run[r] = mn;
#pragma unroll
      for (int di = 0; di < 8; di++) oacc[di][r] *= alpha;
    }

    // ---- P -> LDS (wave-private), C-layout -> A-layout
#pragma unroll
    for (int ni = 0; ni < 4; ni++)
#pragma unroll
      for (int r = 0; r < 4; r++)
        Ps[w][(g * 4 + r) * 72 + ni * 16 + r16] = (__bf16)sf[ni][r];

    // ---- O += P @ V
#pragma unroll
    for (int ks2 = 0; ks2 < 2; ks2++) {
      bf16x8 pa = *(const bf16x8*)&Ps[w][r16 * 72 + ks2 * 32 + g * 8];
#pragma unroll
      for (int di = 0; di < 8; di++) {
        int d_ = di * 16 + r16;
        int off = ((d_ << 7) + (ks2 * 32 + g * 8) * 2) ^ ((d_ & 7) << 4);
        bf16x8 vf = *(const bf16x8*)((const char*)Vs + off);
        oacc[di] = __builtin_amdgcn_mfma_f32_16x16x32_bf16(pa, vf, oacc[di], 0, 0, 0);
      }
    }
    __syncthreads();   // protect single buffer before next stage
  }

  // ---- epilogue
#pragma unroll
  for (int r = 0; r < 4; r++) {
    float inv = 1.0f / l_run[r];
    size_t rowb = ((size_t)b * 2048 + q0 + w * 16 + g * 4 + r) * 2048 + head * 128 + r16;
#pragma unroll
    for (int di = 0; di < 8; di++)
      Ob[rowb + di * 16] = (__bf16)(oacc[di][r] * inv);
  }
}

// ---------------- host ----------------
extern "C" void kernel_launch(void* const* d_in, const int* in_sizes, int n_in,
                              void* d_out, int out_size, void* d_ws, size_t ws_size,
                              hipStream_t stream) {
  const float* X  = (const float*)d_in[0];
  const float* Wi = (const float*)d_in[1];
  const float* bi = (const float*)d_in[2];
  const float* Wo = (const float*)d_in[3];
  const float* bo = (const float*)d_in[4];
  float* out = (float*)d_out;

  char* p = (char*)d_ws;
  auto alloc = [&](size_t bytes) {
    char* r = p;
    p += (bytes + 255) & ~(size_t)255;
    return r;
  };
  __bf16* Xb  = (__bf16*)alloc((size_t)4096 * 2048 * 2);
  __bf16* Wib = (__bf16*)alloc((size_t)6144 * 2048 * 2);
  __bf16* Wob = (__bf16*)alloc((size_t)2048 * 2048 * 2);
  __bf16* Qb  = (__bf16*)alloc((size_t)32 * 2048 * 128 * 2);
  __bf16* Kb  = (__bf16*)alloc((size_t)32 * 2048 * 128 * 2);
  __bf16* Vb  = (__bf16*)alloc((size_t)32 * 2048 * 128 * 2);   // [bh][d][s]
  __bf16* Ab  = (__bf16*)alloc((size_t)4096 * 2048 * 2);

  {
    int n4 = 4096 * 2048 / 4;
    f2bf_kernel<<<(n4 + 255) / 256, 256, 0, stream>>>(X, Xb, n4);
  }
  {
    int n4 = 6144 * 2048 / 4;
    f2bf_kernel<<<(n4 + 255) / 256, 256, 0, stream>>>(Wi, Wib, n4);
  }
  {
    int n4 = 2048 * 2048 / 4;
    f2bf_kernel<<<(n4 + 255) / 256, 256, 0, stream>>>(Wo, Wob, n4);
  }

  gemm256<0><<<dim3(384), 512, 0, stream>>>(Xb, Wib, bi, Qb, Kb, Vb, nullptr);
  attn_kernel<<<dim3(1024), 256, 0, stream>>>(Qb, Kb, Vb, Ab);
  gemm256<1><<<dim3(128), 512, 0, stream>>>(Ab, Wob, bo, nullptr, nullptr, nullptr, out);
}

// Round 5
// 412.236 us; speedup vs baseline: 1.8012x; 1.0073x over previous
//
#include <hip/hip_runtime.h>
#include <cstdint>

typedef __bf16 bf16x8 __attribute__((ext_vector_type(8)));
typedef __bf16 bf16x4 __attribute__((ext_vector_type(4)));
typedef float  f32x4  __attribute__((ext_vector_type(4)));

__device__ __forceinline__ void lds_load16(const void* g, void* l) {
  __builtin_amdgcn_global_load_lds(
      (const __attribute__((address_space(1))) unsigned int*)g,
      (__attribute__((address_space(3))) unsigned int*)l, 16, 0, 0);
}

#define BAR() do { asm volatile("" ::: "memory"); __builtin_amdgcn_s_barrier(); asm volatile("" ::: "memory"); } while (0)

__device__ __forceinline__ float grp16_max(float v) {
  v = fmaxf(v, __shfl_xor(v, 1));
  v = fmaxf(v, __shfl_xor(v, 2));
  v = fmaxf(v, __shfl_xor(v, 4));
  v = fmaxf(v, __shfl_xor(v, 8));
  return v;
}
__device__ __forceinline__ float grp16_sum(float v) {
  v += __shfl_xor(v, 1);
  v += __shfl_xor(v, 2);
  v += __shfl_xor(v, 4);
  v += __shfl_xor(v, 8);
  return v;
}

// ---------------- fp32 -> bf16 conversion ----------------
__global__ void f2bf_kernel(const float* __restrict__ in, __bf16* __restrict__ out, int n4) {
  int i = blockIdx.x * blockDim.x + threadIdx.x;
  if (i >= n4) return;
  const float4 v = reinterpret_cast<const float4*>(in)[i];
  bf16x4 o;
  o[0] = (__bf16)v.x; o[1] = (__bf16)v.y; o[2] = (__bf16)v.z; o[3] = (__bf16)v.w;
  reinterpret_cast<bf16x4*>(out)[i] = o;
}

// ================= 256xBN 2-tile-deep pipelined GEMM =================
// C = A @ B^T + bias. A[M][K], B[N][K] bf16. 512 threads = 8 waves (2M x 4N).
// BM=256, BK=64. LDS halves split by interleaved 16-row stripes so that the
// kt+2 stage of each half lands one phase after that half's reads drained:
//   ph1: read A mf0-3 + B nf[0,NH)          | MFMA Q1 = mf0-3 x nf[0,NH)
//   ph2: read B nf[NH,NF); stage B-h0(kt+2) | MFMA Q2 = mf0-3 x nf[NH,NF)
//   ph3: read A mf4-7; stage A-h0 + B-h1    | MFMA Q3 = mf4-7 x nf[0,NH)
//   ph4: stage A-h1; vmcnt(LPT)             | MFMA Q4 = mf4-7 x nf[NH,NF)
// Every load gets >= 1 full tile of latency cover (counted vmcnt, never 0 midloop).
// EPI==0: QKV scatter (N=6144, grid 384). EPI==1: fp32 out (BN=128, N=2048, grid 256).
template <int BN, int EPI>
__global__ __launch_bounds__(512, 1)
void gemm256(const __bf16* __restrict__ A, const __bf16* __restrict__ Bm,
             const float* __restrict__ bias,
             __bf16* __restrict__ qo, __bf16* __restrict__ ko, __bf16* __restrict__ vo,
             float* __restrict__ co)
{
  constexpr int K = 2048, NT = K / 64;
  constexpr int NF = BN / 64;           // n-frags per wave (4 or 2)
  constexpr int NH = NF / 2;
  constexpr int ABYTES = 32768;         // 256 x 64 x 2B
  constexpr int BBYTES = BN * 128;
  constexpr int HB = BBYTES / 2;
  constexpr int BUFB = ABYTES + BBYTES;
  constexpr int BLOADS = BN / 128;      // gloads per B half per thread (2 or 1)
  constexpr int LPT = 4 + 2 * BLOADS;   // loads per tile per thread (8 or 6)
  __shared__ __align__(16) char lds8[2 * BUFB];

  const int t = threadIdx.x;
  const int lane = t & 63, w = t >> 6;
  const int g = lane >> 4, r16 = lane & 15;
  const int wm = w >> 2, wn = w & 3;

  const int bid = blockIdx.x;
  int tM, tN;
  if (EPI == 0) {
    const int swz = (bid & 7) * 48 + (bid >> 3);   // 384 blocks: 16 M x 24 N
    tM = (swz & 15) * 256;
    tN = (swz >> 4) * 256;
  } else {
    const int swz = (bid & 7) * 32 + (bid >> 3);   // 256 blocks: 16 M x 16 N
    tM = (swz & 15) * 256;
    tN = (swz >> 4) * BN;
  }

  const char* Ag = (const char*)A + (size_t)tM * K * 2;
  const char* Bg = (const char*)Bm + (size_t)tN * K * 2;
  const int ld = K * 2;

  // A half h = stripes {mf: mf>>2 == h} for both wm. LDS A: [half][8 slots][16][128B]
  auto STAGE_A = [&](int h, int tb, int ktg) {
#pragma unroll
    for (int i = 0; i < 2; i++) {
      int o = i * 8192 + t * 16;
      int slot = o >> 11;                 // wm' = slot>>2, mfq = slot&3
      int row  = (o >> 7) & 15;
      int inb  = (o & 127) ^ ((row & 7) << 4);
      int grow = (slot >> 2) * 128 + (h * 4 + (slot & 3)) * 16 + row;
      lds_load16(Ag + (size_t)grow * ld + (size_t)ktg * 128 + inb,
                 lds8 + tb * BUFB + h * 16384 + o);
    }
  };
  // B half h = stripes {nf: nf/NH == h}. LDS B: [half][slots][16][128B]
  auto STAGE_B = [&](int h, int tb, int ktg) {
#pragma unroll
    for (int i = 0; i < BLOADS; i++) {
      int o = i * 8192 + t * 16;
      int slot = o >> 11;
      int row  = (o >> 7) & 15;
      int inb  = (o & 127) ^ ((row & 7) << 4);
      int grow;
      if (BN == 256) grow = (slot >> 1) * 64 + (h * 2 + (slot & 1)) * 16 + row;
      else           grow = slot * 32 + h * 16 + row;
      lds_load16(Bg + (size_t)grow * ld + (size_t)ktg * 128 + inb,
                 lds8 + tb * BUFB + ABYTES + h * HB + o);
    }
  };

  const int inA = (g * 16) ^ ((r16 & 7) << 4);
  const int rbase = r16 * 128;

  f32x4 acc[8][NF] = {};
  bf16x8 af0[4][2], af1[4][2];
  bf16x8 bfm[NF][2];

  // ---- prologue: tile0 -> buf0, tile1 -> buf1; drain tile0 only
  STAGE_A(0, 0, 0); STAGE_A(1, 0, 0); STAGE_B(0, 0, 0); STAGE_B(1, 0, 0);
  STAGE_A(0, 1, 1); STAGE_A(1, 1, 1); STAGE_B(0, 1, 1); STAGE_B(1, 1, 1);
  if (LPT == 8) { asm volatile("s_waitcnt vmcnt(8)" ::: "memory"); }
  else          { asm volatile("s_waitcnt vmcnt(6)" ::: "memory"); }
  __builtin_amdgcn_s_barrier();

  for (int kt = 0; kt < NT; ++kt) {
    const int cb = kt & 1;
    const char* aT = lds8 + cb * BUFB;
    const char* bT = aT + ABYTES;

    // ---- ph1: read A mf0-3 + B nf[0,NH); MFMA Q1
#pragma unroll
    for (int mq = 0; mq < 4; mq++)
#pragma unroll
      for (int ks = 0; ks < 2; ks++)
        af0[mq][ks] = *(const bf16x8*)(aT + (wm * 4 + mq) * 2048 + rbase + (inA ^ (ks * 64)));
#pragma unroll
    for (int nf = 0; nf < NH; nf++) {
      int slot = (BN == 256) ? (wn * 2 + nf) : wn;
#pragma unroll
      for (int ks = 0; ks < 2; ks++)
        bfm[nf][ks] = *(const bf16x8*)(bT + slot * 2048 + rbase + (inA ^ (ks * 64)));
    }
    BAR();
    __builtin_amdgcn_s_setprio(1);
#pragma unroll
    for (int mq = 0; mq < 4; mq++)
#pragma unroll
      for (int nf = 0; nf < NH; nf++)
#pragma unroll
        for (int ks = 0; ks < 2; ks++)
          acc[mq][nf] = __builtin_amdgcn_mfma_f32_16x16x32_bf16(af0[mq][ks], bfm[nf][ks], acc[mq][nf], 0, 0, 0);
    __builtin_amdgcn_s_setprio(0);
    BAR();

    // ---- ph2: read B nf[NH,NF); stage B-h0(kt+2); MFMA Q2
#pragma unroll
    for (int nf = NH; nf < NF; nf++) {
      int slot = (BN == 256) ? (wn * 2 + (nf & 1)) : wn;
#pragma unroll
      for (int ks = 0; ks < 2; ks++)
        bfm[nf][ks] = *(const bf16x8*)(bT + HB + slot * 2048 + rbase + (inA ^ (ks * 64)));
    }
    if (kt + 2 < NT) STAGE_B(0, cb, kt + 2);
    BAR();
    __builtin_amdgcn_s_setprio(1);
#pragma unroll
    for (int mq = 0; mq < 4; mq++)
#pragma unroll
      for (int nf = NH; nf < NF; nf++)
#pragma unroll
        for (int ks = 0; ks < 2; ks++)
          acc[mq][nf] = __builtin_amdgcn_mfma_f32_16x16x32_bf16(af0[mq][ks], bfm[nf][ks], acc[mq][nf], 0, 0, 0);
    __builtin_amdgcn_s_setprio(0);
    BAR();

    // ---- ph3: read A mf4-7; stage A-h0 + B-h1(kt+2); MFMA Q3
#pragma unroll
    for (int mq = 0; mq < 4; mq++)
#pragma unroll
      for (int ks = 0; ks < 2; ks++)
        af1[mq][ks] = *(const bf16x8*)(aT + 16384 + (wm * 4 + mq) * 2048 + rbase + (inA ^ (ks * 64)));
    if (kt + 2 < NT) { STAGE_A(0, cb, kt + 2); STAGE_B(1, cb, kt + 2); }
    BAR();
    __builtin_amdgcn_s_setprio(1);
#pragma unroll
    for (int mq = 0; mq < 4; mq++)
#pragma unroll
      for (int nf = 0; nf < NH; nf++)
#pragma unroll
        for (int ks = 0; ks < 2; ks++)
          acc[mq + 4][nf] = __builtin_amdgcn_mfma_f32_16x16x32_bf16(af1[mq][ks], bfm[nf][ks], acc[mq + 4][nf], 0, 0, 0);
    __builtin_amdgcn_s_setprio(0);
    BAR();

    // ---- ph4: stage A-h1(kt+2); MFMA Q4; counted drain
    if (kt + 2 < NT) STAGE_A(1, cb, kt + 2);
    BAR();
    __builtin_amdgcn_s_setprio(1);
#pragma unroll
    for (int mq = 0; mq < 4; mq++)
#pragma unroll
      for (int nf = NH; nf < NF; nf++)
#pragma unroll
        for (int ks = 0; ks < 2; ks++)
          acc[mq + 4][nf] = __builtin_amdgcn_mfma_f32_16x16x32_bf16(af1[mq][ks], bfm[nf][ks], acc[mq + 4][nf], 0, 0, 0);
    __builtin_amdgcn_s_setprio(0);
    if (kt + 2 < NT) {
      if (LPT == 8) { asm volatile("s_waitcnt vmcnt(8)" ::: "memory"); }
      else          { asm volatile("s_waitcnt vmcnt(6)" ::: "memory"); }
    } else {
      asm volatile("s_waitcnt vmcnt(0)" ::: "memory");
    }
    BAR();
  }

  if (EPI == 0) {
#pragma unroll
    for (int nf = 0; nf < NF; nf++) {
      int col = tN + wn * 64 + nf * 16 + r16;
      float bv = bias[col];
      int which = col >> 11;
      int f = col & 2047;
      int head = f >> 7, dd = f & 127;
      if (which == 2) {
#pragma unroll
        for (int mf = 0; mf < 8; mf++)
#pragma unroll
          for (int r = 0; r < 4; r++) {
            int m = tM + wm * 128 + mf * 16 + g * 4 + r;
            int bb2 = m >> 11, s = m & 2047;
            vo[((size_t)(bb2 * 16 + head) * 128 + dd) * 2048 + s] = (__bf16)(acc[mf][nf][r] + bv);
          }
      } else {
        __bf16* dst = (which == 0) ? qo : ko;
        float sc = (which == 0) ? 0.12751757f : 1.0f;   // log2e/sqrt(128) folded into Q
#pragma unroll
        for (int mf = 0; mf < 8; mf++)
#pragma unroll
          for (int r = 0; r < 4; r++) {
            int m = tM + wm * 128 + mf * 16 + g * 4 + r;
            int bb2 = m >> 11, s = m & 2047;
            dst[((size_t)(bb2 * 16 + head) * 2048 + s) * 128 + dd] = (__bf16)((acc[mf][nf][r] + bv) * sc);
          }
      }
    }
  } else {
    constexpr int N = 2048;
#pragma unroll
    for (int nf = 0; nf < NF; nf++) {
      int col = tN + wn * (BN / 4) + nf * 16 + r16;
      float bv = bias[col];
#pragma unroll
      for (int mf = 0; mf < 8; mf++)
#pragma unroll
        for (int r = 0; r < 4; r++) {
          int m = tM + wm * 128 + mf * 16 + g * 4 + r;
          co[(size_t)m * N + col] = acc[mf][nf][r] + bv;
        }
    }
  }
}

// ---------------- causal flash attention ----------------
// 1D grid 1024: qi = 31 - (bid>>5) (longest-first), bh = bid&31 (bid%8==bh%8 -> XCD locality).
// 256 threads = 4 waves, 16 q-rows/wave. Single-buffered K/V (42 KB LDS, 3 blocks/CU).
__global__ __launch_bounds__(256)
void attn_kernel(const __bf16* __restrict__ Qb, const __bf16* __restrict__ Kb,
                 const __bf16* __restrict__ Vb, __bf16* __restrict__ Ob)
{
  const int bid = blockIdx.x;
  const int qi = 31 - (bid >> 5);
  const int bh = bid & 31;
  const int b = bh >> 4, head = bh & 15;
  const int t = threadIdx.x, lane = t & 63, w = t >> 6;
  const int g = lane >> 4, r16 = lane & 15;

  __shared__ __align__(16) __bf16 Ks[64 * 128];
  __shared__ __align__(16) __bf16 Vs[128 * 64];
  __shared__ __align__(16) __bf16 Ps[4][16 * 72];

  const int q0 = qi * 64;
  const size_t hoff = (size_t)bh * 2048 * 128;
  const char* Kt0 = (const char*)(Kb + hoff);
  const char* Vt0 = (const char*)(Vb + hoff);

  bf16x8 qf[4];
  {
    const __bf16* qp = Qb + hoff + (size_t)(q0 + w * 16 + r16) * 128 + g * 8;
#pragma unroll
    for (int ks = 0; ks < 4; ks++) qf[ks] = *(const bf16x8*)(qp + ks * 32);
  }

  f32x4 oacc[8] = {};
  float m_run[4], l_run[4];
#pragma unroll
  for (int r = 0; r < 4; r++) { m_run[r] = -1e30f; l_run[r] = 0.f; }

  for (int kt = 0; kt <= qi; ++kt) {
#pragma unroll
    for (int it = 0; it < 4; it++) {
      int o = it * 4096 + t * 16;
      int swz = o ^ (((o >> 8) & 7) << 4);
      lds_load16(Kt0 + (size_t)kt * 16384 + swz, (char*)Ks + o);
    }
#pragma unroll
    for (int it = 0; it < 4; it++) {
      int o = it * 4096 + t * 16;
      int swz = o ^ (((o >> 7) & 7) << 4);
      lds_load16(Vt0 + (size_t)kt * 128 + (size_t)(swz >> 7) * 4096 + (swz & 127), (char*)Vs + o);
    }
    __syncthreads();

    f32x4 sf[4];
#pragma unroll
    for (int ni = 0; ni < 4; ni++) {
      f32x4 a = {};
#pragma unroll
      for (int ks = 0; ks < 4; ks++) {
        int row = ni * 16 + r16;
        int off = (row * 256 + (ks * 32 + g * 8) * 2) ^ ((row & 7) << 4);
        bf16x8 kf = *(const bf16x8*)((const char*)Ks + off);
        a = __builtin_amdgcn_mfma_f32_16x16x32_bf16(qf[ks], kf, a, 0, 0, 0);
      }
      sf[ni] = a;
    }

    if (kt == qi) {
#pragma unroll
      for (int ni = 0; ni < 4; ni++) {
        int kg = kt * 64 + ni * 16 + r16;
#pragma unroll
        for (int r = 0; r < 4; r++) {
          int qg = q0 + w * 16 + g * 4 + r;
          if (kg > qg) sf[ni][r] = -1e30f;
        }
      }
    }

#pragma unroll
    for (int r = 0; r < 4; r++) {
      float mx = fmaxf(fmaxf(sf[0][r], sf[1][r]), fmaxf(sf[2][r], sf[3][r]));
      mx = grp16_max(mx);
      float mn = fmaxf(m_run[r], mx);
      float alpha = __builtin_amdgcn_exp2f(m_run[r] - mn);
      float ps = 0.f;
#pragma unroll
      for (int ni = 0; ni < 4; ni++) {
        float p = __builtin_amdgcn_exp2f(sf[ni][r] - mn);
        sf[ni][r] = p; ps += p;
      }
      ps = grp16_sum(ps);
      l_run[r] = l_run[r] * alpha + ps;
      m_run[r] = mn;
#pragma unroll
      for (int di = 0; di < 8; di++) oacc[di][r] *= alpha;
    }

#pragma unroll
    for (int ni = 0; ni < 4; ni++)
#pragma unroll
      for (int r = 0; r < 4; r++)
        Ps[w][(g * 4 + r) * 72 + ni * 16 + r16] = (__bf16)sf[ni][r];

#pragma unroll
    for (int ks2 = 0; ks2 < 2; ks2++) {
      bf16x8 pa = *(const bf16x8*)&Ps[w][r16 * 72 + ks2 * 32 + g * 8];
#pragma unroll
      for (int di = 0; di < 8; di++) {
        int d_ = di * 16 + r16;
        int off = ((d_ << 7) + (ks2 * 32 + g * 8) * 2) ^ ((d_ & 7) << 4);
        bf16x8 vf = *(const bf16x8*)((const char*)Vs + off);
        oacc[di] = __builtin_amdgcn_mfma_f32_16x16x32_bf16(pa, vf, oacc[di], 0, 0, 0);
      }
    }
    __syncthreads();
  }

#pragma unroll
  for (int r = 0; r < 4; r++) {
    float inv = 1.0f / l_run[r];
    size_t rowb = ((size_t)b * 2048 + q0 + w * 16 + g * 4 + r) * 2048 + head * 128 + r16;
#pragma unroll
    for (int di = 0; di < 8; di++)
      Ob[rowb + di * 16] = (__bf16)(oacc[di][r] * inv);
  }
}

// ---------------- host ----------------
extern "C" void kernel_launch(void* const* d_in, const int* in_sizes, int n_in,
                              void* d_out, int out_size, void* d_ws, size_t ws_size,
                              hipStream_t stream) {
  const float* X  = (const float*)d_in[0];
  const float* Wi = (const float*)d_in[1];
  const float* bi = (const float*)d_in[2];
  const float* Wo = (const float*)d_in[3];
  const float* bo = (const float*)d_in[4];
  float* out = (float*)d_out;

  char* p = (char*)d_ws;
  auto alloc = [&](size_t bytes) {
    char* r = p;
    p += (bytes + 255) & ~(size_t)255;
    return r;
  };
  __bf16* Xb  = (__bf16*)alloc((size_t)4096 * 2048 * 2);
  __bf16* Wib = (__bf16*)alloc((size_t)6144 * 2048 * 2);
  __bf16* Wob = (__bf16*)alloc((size_t)2048 * 2048 * 2);
  __bf16* Qb  = (__bf16*)alloc((size_t)32 * 2048 * 128 * 2);
  __bf16* Kb  = (__bf16*)alloc((size_t)32 * 2048 * 128 * 2);
  __bf16* Vb  = (__bf16*)alloc((size_t)32 * 2048 * 128 * 2);   // [bh][d][s]
  __bf16* Ab  = (__bf16*)alloc((size_t)4096 * 2048 * 2);

  {
    int n4 = 4096 * 2048 / 4;
    f2bf_kernel<<<(n4 + 255) / 256, 256, 0, stream>>>(X, Xb, n4);
  }
  {
    int n4 = 6144 * 2048 / 4;
    f2bf_kernel<<<(n4 + 255) / 256, 256, 0, stream>>>(Wi, Wib, n4);
  }
  {
    int n4 = 2048 * 2048 / 4;
    f2bf_kernel<<<(n4 + 255) / 256, 256, 0, stream>>>(Wo, Wob, n4);
  }

  gemm256<256, 0><<<dim3(384), 512, 0, stream>>>(Xb, Wib, bi, Qb, Kb, Vb, nullptr);
  attn_kernel<<<dim3(1024), 256, 0, stream>>>(Qb, Kb, Vb, Ab);
  gemm256<128, 1><<<dim3(256), 512, 0, stream>>>(Ab, Wob, bo, nullptr, nullptr, nullptr, out);
}